// Round 1
// baseline (112.800 us; speedup 1.0000x reference)
//
#include <hip/hip_runtime.h>

// VisitEncoder: out[v,:] = mean over valid codes j of logmap0(emb[ids[v,j]]), c=1.
//
// R10: keep R9's 3-kernel global-scale int8 structure; rework the gather:
//   * K3 gathers dwordx4 (16B/lane, 4 lanes/row): 16 rows per VMEM instr
//     (was 8), 6 gather instrs per wave-pair (was 12). Same line traffic,
//     same accumulate VALU (bytes/lane unchanged).
//   * zero-row padding: tab has C+1 rows, row C = zeros; id<0 gathers row C
//     (one hot line) -> drops the 8 mask-ANDs/iter. Bit-identical math.
//   * nontemporal ids loads + out stores: stream-once data stops evicting
//     the 6.4MB table from L2 during the gather.
//   * K1 grid 256->1024 blocks (4 blocks/CU) + 2 loads in flight: amax scan
//     was 1 block/CU latency-bound.
// Precision: unchanged vs R9 (global qs = amax*1.0006/127); measured absmax
// was 1.14e-5.

#define LCODES 48
#define DIM 64

typedef float vf4 __attribute__((ext_vector_type(4)));

// ---------- K1: block-max of |emb| (positive-float bits are monotone) ----------
__global__ __launch_bounds__(256)
void amax_kernel(const float* __restrict__ emb, unsigned* __restrict__ bmax,
                 long n4) {
    const uint4* __restrict__ u4 = reinterpret_cast<const uint4*>(emb);
    const long T = (long)gridDim.x * 256;
    unsigned m = 0;
    for (long i = (long)blockIdx.x * 256 + threadIdx.x; i < n4; i += 2 * T) {
        const uint4 a = u4[i];
        m = max(m, a.x & 0x7fffffffu);
        m = max(m, a.y & 0x7fffffffu);
        m = max(m, a.z & 0x7fffffffu);
        m = max(m, a.w & 0x7fffffffu);
        if (i + T < n4) {
            const uint4 b = u4[i + T];
            m = max(m, b.x & 0x7fffffffu);
            m = max(m, b.y & 0x7fffffffu);
            m = max(m, b.z & 0x7fffffffu);
            m = max(m, b.w & 0x7fffffffu);
        }
    }
    #pragma unroll
    for (int d = 1; d <= 32; d <<= 1)
        m = max(m, (unsigned)__shfl_xor((int)m, d, 64));
    __shared__ unsigned sm[4];
    if ((threadIdx.x & 63) == 0) sm[threadIdx.x >> 6] = m;
    __syncthreads();
    if (threadIdx.x == 0)
        bmax[blockIdx.x] = max(max(sm[0], sm[1]), max(sm[2], sm[3]));
}

__device__ __forceinline__ float global_amax1024(const unsigned* __restrict__ bmax) {
    const int lane = threadIdx.x & 63;
    unsigned m = 0;
    #pragma unroll
    for (int k = 0; k < 16; ++k)
        m = max(m, bmax[lane + 64 * k]);
    #pragma unroll
    for (int d = 1; d <= 32; d <<= 1)
        m = max(m, (unsigned)__shfl_xor((int)m, d, 64));
    return __uint_as_float(m);
}

// ---------- K2: fp32 emb -> uint8 table (C+1 rows, row C = zeros) ----------
__global__ __launch_bounds__(256)
void build_i8_kernel(const float* __restrict__ emb,
                     const unsigned* __restrict__ bmax,
                     unsigned char* __restrict__ tab,
                     float* __restrict__ qsout, int C) {
    const float amax = global_amax1024(bmax);
    // 1.0006 bounds the artanh scale factor (ss <= 64*amax^2 -> scale <= 1.00056)
    const float qs   = amax * (1.0006f / 127.f);
    const float invq = (amax > 0.f) ? (127.f / (amax * 1.0006f)) : 0.f;
    if (blockIdx.x == 0 && threadIdx.x == 0) qsout[0] = qs;
    // zero-row for padded ids (gathers of id<0 land here)
    if (blockIdx.x == 0 && threadIdx.x < 16)
        reinterpret_cast<unsigned*>(tab + (size_t)C * DIM)[threadIdx.x] = 0u;

    const int tid  = threadIdx.x;
    const int lane = tid & 63;
    const int wave = tid >> 6;
    const int g = lane >> 3, s = lane & 7;
    const int r = blockIdx.x * 32 + wave * 8 + g;
    if (r >= C) return;

    const float4* __restrict__ emb4 = reinterpret_cast<const float4*>(emb);
    const float4 a = emb4[r * 16 + 2 * s];       // dims 8s..8s+3
    const float4 b = emb4[r * 16 + 2 * s + 1];   // dims 8s+4..8s+7

    float ss = a.x*a.x + a.y*a.y + a.z*a.z + a.w*a.w
             + b.x*b.x + b.y*b.y + b.z*b.z + b.w*b.w;
    ss += __shfl_xor(ss, 1, 64);
    ss += __shfl_xor(ss, 2, 64);
    ss += __shfl_xor(ss, 4, 64);

    float scale;
    if (__builtin_expect(ss > 0.04f, 0)) {
        // exact artanh path (never taken for this data; correctness guard)
        const float norm = fmaxf(sqrtf(ss), 1e-15f);
        const float arg  = fminf(norm, 1.f - 1e-7f);
        scale = 0.5f * logf((1.f + arg) / (1.f - arg)) / norm;
    } else {
        // artanh(z)/z = 1 + z^2/3 + z^4/5 + z^6/7,  z^2 = ss
        scale = 1.f + ss * (0.33333333333f + ss * (0.2f + ss * 0.14285714285f));
    }
    scale *= invq;   // fold quantization step into the tangent scale

    const float t[8] = { a.x*scale, a.y*scale, a.z*scale, a.w*scale,
                         b.x*scale, b.y*scale, b.z*scale, b.w*scale };
    unsigned u[8];
    #pragma unroll
    for (int k = 0; k < 8; ++k)
        u[k] = (unsigned)((int)rintf(t[k]) + 128);   // in [1,255]

    uint2 w;
    w.x = u[0] | (u[1] << 8) | (u[2] << 16) | (u[3] << 24);
    w.y = u[4] | (u[5] << 8) | (u[6] << 16) | (u[7] << 24);
    reinterpret_cast<uint2*>(tab)[r * 8 + s] = w;   // 64B/row, coalesced
}

// ---------- K3: masked gather-mean, 2 visits/wave, dwordx4 gathers ----------
__global__ __launch_bounds__(256)
void visit_gather_i8x4_kernel(const int* __restrict__ ids,
                              const unsigned char* __restrict__ tab,
                              const float* __restrict__ qsp,
                              float* __restrict__ out, int N, int C) {
    const float qs = qsp[0];          // uniform scalar load, hot line

    const int tid  = threadIdx.x;
    const int lane = tid & 63;
    const int wave = tid >> 6;
    const int v0   = (blockIdx.x * 4 + wave) * 2;   // this wave's visit pair
    if (v0 >= N) return;
    const bool has1 = (v0 + 1) < N;

    // Preload both visits' 48 ids into lanes 0..47 (two coalesced NT loads).
    int myid0 = -1, myid1 = -1;
    if (lane < LCODES) {
        myid0 = __builtin_nontemporal_load(&ids[(long)v0 * LCODES + lane]);
        if (has1)
            myid1 = __builtin_nontemporal_load(&ids[(long)(v0 + 1) * LCODES + lane]);
    }

    const float cnt0 = (float)__popcll(__ballot(myid0 >= 0));
    const float cnt1 = (float)__popcll(__ballot(myid1 >= 0));

    const int g = lane >> 2;   // which of 16 codes this iteration
    const int s = lane & 3;    // uint4 slot = dims [16s..16s+15]
    const uint4* __restrict__ tab4 = reinterpret_cast<const uint4*>(tab);

    // Packed accumulators: each u32 = two 16-bit sums (even/odd bytes).
    // aE*[k]/aO*[k] cover dims 16s+4k+{0,2} / {1,3}. Max 48*255 < 2^16: exact.
    unsigned aE0[4] = {0,0,0,0}, aO0[4] = {0,0,0,0};
    unsigned aE1[4] = {0,0,0,0}, aO1[4] = {0,0,0,0};

    #pragma unroll
    for (int it = 0; it < LCODES / 16; ++it) {
        const int j   = it * 16 + g;
        const int id0 = __shfl(myid0, j, 64);            // group-uniform
        const int id1 = __shfl(myid1, j, 64);
        // padded ids gather the zero row C (single L1-hot line, no masking)
        const unsigned b0 = ((unsigned)(id0 >= 0 ? id0 : C)) << 2;
        const unsigned b1 = ((unsigned)(id1 >= 0 ? id1 : C)) << 2;

        const uint4 w0 = tab4[b0 + s];   // 16 rows per instr, 6 instrs in flight
        const uint4 w1 = tab4[b1 + s];

        aE0[0] +=  w0.x       & 0x00ff00ffu;
        aO0[0] += (w0.x >> 8) & 0x00ff00ffu;
        aE0[1] +=  w0.y       & 0x00ff00ffu;
        aO0[1] += (w0.y >> 8) & 0x00ff00ffu;
        aE0[2] +=  w0.z       & 0x00ff00ffu;
        aO0[2] += (w0.z >> 8) & 0x00ff00ffu;
        aE0[3] +=  w0.w       & 0x00ff00ffu;
        aO0[3] += (w0.w >> 8) & 0x00ff00ffu;
        aE1[0] +=  w1.x       & 0x00ff00ffu;
        aO1[0] += (w1.x >> 8) & 0x00ff00ffu;
        aE1[1] +=  w1.y       & 0x00ff00ffu;
        aO1[1] += (w1.y >> 8) & 0x00ff00ffu;
        aE1[2] +=  w1.z       & 0x00ff00ffu;
        aO1[2] += (w1.z >> 8) & 0x00ff00ffu;
        aE1[3] +=  w1.w       & 0x00ff00ffu;
        aO1[3] += (w1.w >> 8) & 0x00ff00ffu;
    }

    // Combine the 16 g-groups (lane bits 2..5). After this every lane holds
    // the totals for its s-slot (dims 16s..16s+15) for both visits.
    #pragma unroll
    for (int d = 4; d <= 32; d <<= 1) {
        #pragma unroll
        for (int k = 0; k < 4; ++k) {
            aE0[k] += (unsigned)__shfl_xor((int)aE0[k], d, 64);
            aO0[k] += (unsigned)__shfl_xor((int)aO0[k], d, 64);
            aE1[k] += (unsigned)__shfl_xor((int)aE1[k], d, 64);
            aO1[k] += (unsigned)__shfl_xor((int)aO1[k], d, 64);
        }
    }

    // Lanes 0..3 write visit v0; lanes 4..7 write visit v0+1 (parallel).
    if (lane < 8) {
        const bool second = lane >= 4;
        if (!second || has1) {
            const int   s4    = lane & 3;
            const int   v     = v0 + (second ? 1 : 0);
            const float cnt   = second ? cnt1 : cnt0;
            const float qinv  = qs / fmaxf(cnt, 1.f);
            const float fbias = 128.f * cnt;   // remove uint8 offset once
            // cnt==0 => sums 0, bias 0 => out 0, matching the reference.
            vf4* o = reinterpret_cast<vf4*>(out) + (long)v * (DIM / 4) + s4 * 4;
            #pragma unroll
            for (int k = 0; k < 4; ++k) {
                const unsigned e = second ? aE1[k] : aE0[k];
                const unsigned oo = second ? aO1[k] : aO0[k];
                vf4 r;
                r.x = ((float)(e  & 0xffffu) - fbias) * qinv;  // dim 16s+4k+0
                r.y = ((float)(oo & 0xffffu) - fbias) * qinv;  // dim 16s+4k+1
                r.z = ((float)(e  >> 16)     - fbias) * qinv;  // dim 16s+4k+2
                r.w = ((float)(oo >> 16)     - fbias) * qinv;  // dim 16s+4k+3
                __builtin_nontemporal_store(r, o + k);
            }
        }
    }
}

// ---------- Fallback (ws too small): R2-style all-fp32 kernel ----------
__global__ __launch_bounds__(256, 4)
void visit_fp32_kernel(const int* __restrict__ ids,
                       const float* __restrict__ emb,
                       float* __restrict__ out, int N) {
    const int tid  = threadIdx.x;
    const int lane = tid & 63;
    const int wave = tid >> 6;
    const int v    = blockIdx.x * 4 + wave;
    if (v >= N) return;

    int myid = -1;
    if (lane < LCODES) myid = ids[(long)v * LCODES + lane];
    const unsigned long long valid = __ballot(myid >= 0);
    const float cnt = (float)__popcll(valid);
    const int g = lane >> 3, s = lane & 7;
    const float4* __restrict__ emb4 = reinterpret_cast<const float4*>(emb);
    float4 accA = make_float4(0.f,0.f,0.f,0.f), accB = make_float4(0.f,0.f,0.f,0.f);
    #pragma unroll
    for (int it = 0; it < LCODES / 8; ++it) {
        const int id = __shfl(myid, it * 8 + g, 64);
        const float keep = (id >= 0) ? 1.f : 0.f;
        const unsigned base = ((unsigned)(id >= 0 ? id : 0)) << 4;
        float4 a = emb4[base + s], b = emb4[base + 8 + s];
        float ss = a.x*a.x + a.y*a.y + a.z*a.z + a.w*a.w
                 + b.x*b.x + b.y*b.y + b.z*b.z + b.w*b.w;
        ss += __shfl_xor(ss, 1, 64);
        ss += __shfl_xor(ss, 2, 64);
        ss += __shfl_xor(ss, 4, 64);
        float scale;
        if (__builtin_expect(__any(ss > 0.04f), 0)) {
            const float norm = fmaxf(sqrtf(ss), 1e-15f);
            const float arg  = fminf(norm, 1.f - 1e-7f);
            scale = 0.5f * logf((1.f + arg) / (1.f - arg)) / norm;
        } else {
            scale = 1.f + ss * (0.33333333333f + ss * (0.2f + ss * 0.14285714285f));
        }
        scale *= keep;
        accA.x += a.x*scale; accA.y += a.y*scale; accA.z += a.z*scale; accA.w += a.w*scale;
        accB.x += b.x*scale; accB.y += b.y*scale; accB.z += b.z*scale; accB.w += b.w*scale;
    }
    #pragma unroll
    for (int d = 8; d <= 32; d <<= 1) {
        accA.x += __shfl_xor(accA.x, d, 64); accA.y += __shfl_xor(accA.y, d, 64);
        accA.z += __shfl_xor(accA.z, d, 64); accA.w += __shfl_xor(accA.w, d, 64);
        accB.x += __shfl_xor(accB.x, d, 64); accB.y += __shfl_xor(accB.y, d, 64);
        accB.z += __shfl_xor(accB.z, d, 64); accB.w += __shfl_xor(accB.w, d, 64);
    }
    if (lane < 8) {
        const float inv = 1.f / fmaxf(cnt, 1.f);
        float4* o = reinterpret_cast<float4*>(out) + (long)v * (DIM / 4);
        o[2*s]   = make_float4(accA.x*inv, accA.y*inv, accA.z*inv, accA.w*inv);
        o[2*s+1] = make_float4(accB.x*inv, accB.y*inv, accB.z*inv, accB.w*inv);
    }
}

extern "C" void kernel_launch(void* const* d_in, const int* in_sizes, int n_in,
                              void* d_out, int out_size, void* d_ws, size_t ws_size,
                              hipStream_t stream) {
    const int*   ids = (const int*)d_in[0];
    const float* emb = (const float*)d_in[1];
    float*       out = (float*)d_out;

    const int N = in_sizes[0] / LCODES;   // 65536 visits
    const int C = in_sizes[1] / DIM;      // 100000 codes

    // ws layout: [0..4KB) bmax[1024] | [4KB..4KB+4) qs | [8KB..) int8 table (C+1 rows)
    const size_t tab_off = 8192;
    const size_t need = tab_off + (size_t)(C + 1) * DIM;   // ~6.4 MB

    if (ws_size >= need) {
        unsigned*      bmax = (unsigned*)d_ws;
        float*         qsp  = (float*)((char*)d_ws + 4096);
        unsigned char* tab  = (unsigned char*)d_ws + tab_off;

        const long n4 = (long)C * DIM / 4;
        hipLaunchKernelGGL(amax_kernel, dim3(1024), dim3(256), 0, stream,
                           emb, bmax, n4);
        const int blocksA = (C + 31) / 32;
        hipLaunchKernelGGL(build_i8_kernel, dim3(blocksA), dim3(256), 0, stream,
                           emb, bmax, tab, qsp, C);
        // 2 visits per wave, 4 waves per block -> 8 visits per block
        const int blocksB = (N + 7) / 8;
        hipLaunchKernelGGL(visit_gather_i8x4_kernel, dim3(blocksB), dim3(256), 0,
                           stream, ids, tab, qsp, out, N, C);
    } else {
        const int blocks = (N + 3) / 4;
        hipLaunchKernelGGL(visit_fp32_kernel, dim3(blocks), dim3(256), 0, stream,
                           ids, emb, out, N);
    }
}

// Round 2
// 105.871 us; speedup vs baseline: 1.0655x; 1.0655x over previous
//
#include <hip/hip_runtime.h>

// VisitEncoder: out[v,:] = mean over valid codes j of logmap0(emb[ids[v,j]]), c=1.
//
// R11: keep the 3-kernel global-scale int8 structure (K1 amax, K2 quantize,
// K3 gather). Rework K3's decomposition: 4 visits per wave, 16 lanes/visit.
//   * 12 independent dwordx4 gathers in flight per wave (was 6) -> 2x the
//     outstanding-miss depth for L2/L3 latency hiding.
//   * ids via per-wave LDS stash (1 ds_read/iter, <=2-way bank alias = free):
//     removes the per-iter shfl+select broadcast.
//   * reduce: 2 butterfly steps x 8 accs = 16 shfl/wave (R10 had 64).
//   * epilogue: every lane writes ONE float4 -> a single fully-coalesced
//     1KB NT store per wave (flat index v0*16+lane).
//   * wave count halves (16384 waves), prologue/epilogue amortized 2x.
//   * table gathers use normal loads (keep table L2-resident); NT only on
//     stream-once ids loads and out stores.
// Math bit-identical to R9/R10: same uint8 values, exact packed-u16 sums
// (48*255 < 2^16), same fbias/qinv epilogue. Expected absmax 1.14e-5.

#define LCODES 48
#define DIM 64

typedef float vf4 __attribute__((ext_vector_type(4)));

// ---------- K1: block-max of |emb| (positive-float bits are monotone) ----------
__global__ __launch_bounds__(256)
void amax_kernel(const float* __restrict__ emb, unsigned* __restrict__ bmax,
                 long n4) {
    const uint4* __restrict__ u4 = reinterpret_cast<const uint4*>(emb);
    const long T = (long)gridDim.x * 256;
    unsigned m = 0;
    for (long i = (long)blockIdx.x * 256 + threadIdx.x; i < n4; i += 2 * T) {
        const uint4 a = u4[i];
        m = max(m, a.x & 0x7fffffffu);
        m = max(m, a.y & 0x7fffffffu);
        m = max(m, a.z & 0x7fffffffu);
        m = max(m, a.w & 0x7fffffffu);
        if (i + T < n4) {
            const uint4 b = u4[i + T];
            m = max(m, b.x & 0x7fffffffu);
            m = max(m, b.y & 0x7fffffffu);
            m = max(m, b.z & 0x7fffffffu);
            m = max(m, b.w & 0x7fffffffu);
        }
    }
    #pragma unroll
    for (int d = 1; d <= 32; d <<= 1)
        m = max(m, (unsigned)__shfl_xor((int)m, d, 64));
    __shared__ unsigned sm[4];
    if ((threadIdx.x & 63) == 0) sm[threadIdx.x >> 6] = m;
    __syncthreads();
    if (threadIdx.x == 0)
        bmax[blockIdx.x] = max(max(sm[0], sm[1]), max(sm[2], sm[3]));
}

__device__ __forceinline__ float global_amax1024(const unsigned* __restrict__ bmax) {
    const int lane = threadIdx.x & 63;
    unsigned m = 0;
    #pragma unroll
    for (int k = 0; k < 16; ++k)
        m = max(m, bmax[lane + 64 * k]);
    #pragma unroll
    for (int d = 1; d <= 32; d <<= 1)
        m = max(m, (unsigned)__shfl_xor((int)m, d, 64));
    return __uint_as_float(m);
}

// ---------- K2: fp32 emb -> uint8 table (C+1 rows, row C = zeros) ----------
__global__ __launch_bounds__(256)
void build_i8_kernel(const float* __restrict__ emb,
                     const unsigned* __restrict__ bmax,
                     unsigned char* __restrict__ tab,
                     float* __restrict__ qsout, int C) {
    const float amax = global_amax1024(bmax);
    // 1.0006 bounds the artanh scale factor (ss <= 64*amax^2 -> scale <= 1.00056)
    const float qs   = amax * (1.0006f / 127.f);
    const float invq = (amax > 0.f) ? (127.f / (amax * 1.0006f)) : 0.f;
    if (blockIdx.x == 0 && threadIdx.x == 0) qsout[0] = qs;
    // zero-row for padded ids (gathers of id<0 land here)
    if (blockIdx.x == 0 && threadIdx.x < 16)
        reinterpret_cast<unsigned*>(tab + (size_t)C * DIM)[threadIdx.x] = 0u;

    const int tid  = threadIdx.x;
    const int lane = tid & 63;
    const int wave = tid >> 6;
    const int g = lane >> 3, s = lane & 7;
    const int r = blockIdx.x * 32 + wave * 8 + g;
    if (r >= C) return;

    const float4* __restrict__ emb4 = reinterpret_cast<const float4*>(emb);
    const float4 a = emb4[r * 16 + 2 * s];       // dims 8s..8s+3
    const float4 b = emb4[r * 16 + 2 * s + 1];   // dims 8s+4..8s+7

    float ss = a.x*a.x + a.y*a.y + a.z*a.z + a.w*a.w
             + b.x*b.x + b.y*b.y + b.z*b.z + b.w*b.w;
    ss += __shfl_xor(ss, 1, 64);
    ss += __shfl_xor(ss, 2, 64);
    ss += __shfl_xor(ss, 4, 64);

    float scale;
    if (__builtin_expect(ss > 0.04f, 0)) {
        // exact artanh path (never taken for this data; correctness guard)
        const float norm = fmaxf(sqrtf(ss), 1e-15f);
        const float arg  = fminf(norm, 1.f - 1e-7f);
        scale = 0.5f * logf((1.f + arg) / (1.f - arg)) / norm;
    } else {
        // artanh(z)/z = 1 + z^2/3 + z^4/5 + z^6/7,  z^2 = ss
        scale = 1.f + ss * (0.33333333333f + ss * (0.2f + ss * 0.14285714285f));
    }
    scale *= invq;   // fold quantization step into the tangent scale

    const float t[8] = { a.x*scale, a.y*scale, a.z*scale, a.w*scale,
                         b.x*scale, b.y*scale, b.z*scale, b.w*scale };
    unsigned u[8];
    #pragma unroll
    for (int k = 0; k < 8; ++k)
        u[k] = (unsigned)((int)rintf(t[k]) + 128);   // in [1,255]

    uint2 w;
    w.x = u[0] | (u[1] << 8) | (u[2] << 16) | (u[3] << 24);
    w.y = u[4] | (u[5] << 8) | (u[6] << 16) | (u[7] << 24);
    reinterpret_cast<uint2*>(tab)[r * 8 + s] = w;   // 64B/row, coalesced
}

// ---------- K3: gather-mean, 4 visits per wave, 16 lanes per visit ----------
__global__ __launch_bounds__(256)
void visit_gather_i8q_kernel(const int* __restrict__ ids,
                             const unsigned char* __restrict__ tab,
                             const float* __restrict__ qsp,
                             float* __restrict__ out, int N, int C) {
    const float qs = qsp[0];          // uniform scalar load, hot line

    const int tid  = threadIdx.x;
    const int lane = tid & 63;
    const int wave = tid >> 6;
    const int v0   = (blockIdx.x * 4 + wave) * 4;   // this wave's visit quad
    if (v0 >= N) return;

    __shared__ int sids[4][4 * LCODES];   // [wave][visit*48 + j], 3KB/block

    // Load 4 visits' ids (lanes 0..47; invalid visits stay -1 -> zero row),
    // stash to LDS (same-wave producer/consumer: no barrier needed).
    int m0 = -1, m1 = -1, m2 = -1, m3 = -1;
    if (lane < LCODES) {
        const long b = (long)v0 * LCODES;
        m0 = __builtin_nontemporal_load(&ids[b + lane]);
        if (v0 + 1 < N) m1 = __builtin_nontemporal_load(&ids[b + LCODES + lane]);
        if (v0 + 2 < N) m2 = __builtin_nontemporal_load(&ids[b + 2 * LCODES + lane]);
        if (v0 + 3 < N) m3 = __builtin_nontemporal_load(&ids[b + 3 * LCODES + lane]);
        sids[wave][lane]              = m0;
        sids[wave][LCODES + lane]     = m1;
        sids[wave][2 * LCODES + lane] = m2;
        sids[wave][3 * LCODES + lane] = m3;
    }
    const float cnt0 = (float)__popcll(__ballot(m0 >= 0));
    const float cnt1 = (float)__popcll(__ballot(m1 >= 0));
    const float cnt2 = (float)__popcll(__ballot(m2 >= 0));
    const float cnt3 = (float)__popcll(__ballot(m3 >= 0));

    const int v = lane >> 4;          // visit within quad
    const int g = (lane >> 2) & 3;    // code-subgroup within iteration
    const int s = lane & 3;           // uint4 slot = dims [16s..16s+15]
    const uint4* __restrict__ tab4 = reinterpret_cast<const uint4*>(tab);
    const int* __restrict__ slid = &sids[wave][v * LCODES + g];

    // Packed accumulators: each u32 = two 16-bit sums (even/odd bytes).
    // aE[k]/aO[k] cover dims 16s+4k+{0,2} / {1,3}. Max 48*255 < 2^16: exact.
    unsigned aE[4] = {0,0,0,0}, aO[4] = {0,0,0,0};

    #pragma unroll
    for (int it = 0; it < LCODES / 4; ++it) {
        const int id = slid[4 * it];                       // <=2-way bank alias: free
        const unsigned base = ((unsigned)(id >= 0 ? id : C)) << 2;
        const uint4 w = tab4[base + s];   // 12 independent gathers in flight
        aE[0] +=  w.x       & 0x00ff00ffu;
        aO[0] += (w.x >> 8) & 0x00ff00ffu;
        aE[1] +=  w.y       & 0x00ff00ffu;
        aO[1] += (w.y >> 8) & 0x00ff00ffu;
        aE[2] +=  w.z       & 0x00ff00ffu;
        aO[2] += (w.z >> 8) & 0x00ff00ffu;
        aE[3] +=  w.w       & 0x00ff00ffu;
        aO[3] += (w.w >> 8) & 0x00ff00ffu;
    }

    // Combine the 4 g-subgroups (lane bits 2..3). After this, every lane
    // holds the full sums for (its visit v, its slot s).
    #pragma unroll
    for (int d = 4; d <= 8; d <<= 1) {
        #pragma unroll
        for (int k = 0; k < 4; ++k) {
            aE[k] += (unsigned)__shfl_xor((int)aE[k], d, 64);
            aO[k] += (unsigned)__shfl_xor((int)aO[k], d, 64);
        }
    }

    // Epilogue: lane writes ONE float4. f = lane&15 -> dims 4f..4f+3 of its
    // visit; owner slot s*=f>>2 lives in lane (lane&0x30)|(f>>2), word k*=f&3.
    const int f   = lane & 15;
    const int src = (lane & 0x30) | (f >> 2);
    const int kk  = lane & 3;
    unsigned e = 0, o = 0;
    #pragma unroll
    for (int k = 0; k < 4; ++k) {
        const unsigned ek = (unsigned)__shfl((int)aE[k], src, 64);
        const unsigned ok = (unsigned)__shfl((int)aO[k], src, 64);
        if (kk == k) { e = ek; o = ok; }
    }
    const float cnt = (v == 0) ? cnt0 : (v == 1) ? cnt1 : (v == 2) ? cnt2 : cnt3;
    const float qinv  = qs / fmaxf(cnt, 1.f);
    const float fbias = 128.f * cnt;   // remove uint8 offset once
    // cnt==0 => sums 0, bias 0 => out 0, matching the reference.
    vf4 r;
    r.x = ((float)(e  & 0xffffu) - fbias) * qinv;   // dim 4f+0
    r.y = ((float)(o  & 0xffffu) - fbias) * qinv;   // dim 4f+1
    r.z = ((float)(e  >> 16)     - fbias) * qinv;   // dim 4f+2
    r.w = ((float)(o  >> 16)     - fbias) * qinv;   // dim 4f+3
    if (v0 + v < N) {
        // flat float4 index = (v0+v)*16 + f = v0*16 + lane: one coalesced
        // 1KB NT store per wave.
        vf4* o4 = reinterpret_cast<vf4*>(out);
        __builtin_nontemporal_store(r, &o4[(long)v0 * 16 + lane]);
    }
}

// ---------- Fallback (ws too small): R2-style all-fp32 kernel ----------
__global__ __launch_bounds__(256, 4)
void visit_fp32_kernel(const int* __restrict__ ids,
                       const float* __restrict__ emb,
                       float* __restrict__ out, int N) {
    const int tid  = threadIdx.x;
    const int lane = tid & 63;
    const int wave = tid >> 6;
    const int v    = blockIdx.x * 4 + wave;
    if (v >= N) return;

    int myid = -1;
    if (lane < LCODES) myid = ids[(long)v * LCODES + lane];
    const unsigned long long valid = __ballot(myid >= 0);
    const float cnt = (float)__popcll(valid);
    const int g = lane >> 3, s = lane & 7;
    const float4* __restrict__ emb4 = reinterpret_cast<const float4*>(emb);
    float4 accA = make_float4(0.f,0.f,0.f,0.f), accB = make_float4(0.f,0.f,0.f,0.f);
    #pragma unroll
    for (int it = 0; it < LCODES / 8; ++it) {
        const int id = __shfl(myid, it * 8 + g, 64);
        const float keep = (id >= 0) ? 1.f : 0.f;
        const unsigned base = ((unsigned)(id >= 0 ? id : 0)) << 4;
        float4 a = emb4[base + s], b = emb4[base + 8 + s];
        float ss = a.x*a.x + a.y*a.y + a.z*a.z + a.w*a.w
                 + b.x*b.x + b.y*b.y + b.z*b.z + b.w*b.w;
        ss += __shfl_xor(ss, 1, 64);
        ss += __shfl_xor(ss, 2, 64);
        ss += __shfl_xor(ss, 4, 64);
        float scale;
        if (__builtin_expect(__any(ss > 0.04f), 0)) {
            const float norm = fmaxf(sqrtf(ss), 1e-15f);
            const float arg  = fminf(norm, 1.f - 1e-7f);
            scale = 0.5f * logf((1.f + arg) / (1.f - arg)) / norm;
        } else {
            scale = 1.f + ss * (0.33333333333f + ss * (0.2f + ss * 0.14285714285f));
        }
        scale *= keep;
        accA.x += a.x*scale; accA.y += a.y*scale; accA.z += a.z*scale; accA.w += a.w*scale;
        accB.x += b.x*scale; accB.y += b.y*scale; accB.z += b.z*scale; accB.w += b.w*scale;
    }
    #pragma unroll
    for (int d = 8; d <= 32; d <<= 1) {
        accA.x += __shfl_xor(accA.x, d, 64); accA.y += __shfl_xor(accA.y, d, 64);
        accA.z += __shfl_xor(accA.z, d, 64); accA.w += __shfl_xor(accA.w, d, 64);
        accB.x += __shfl_xor(accB.x, d, 64); accB.y += __shfl_xor(accB.y, d, 64);
        accB.z += __shfl_xor(accB.z, d, 64); accB.w += __shfl_xor(accB.w, d, 64);
    }
    if (lane < 8) {
        const float inv = 1.f / fmaxf(cnt, 1.f);
        float4* o = reinterpret_cast<float4*>(out) + (long)v * (DIM / 4);
        o[2*s]   = make_float4(accA.x*inv, accA.y*inv, accA.z*inv, accA.w*inv);
        o[2*s+1] = make_float4(accB.x*inv, accB.y*inv, accB.z*inv, accB.w*inv);
    }
}

extern "C" void kernel_launch(void* const* d_in, const int* in_sizes, int n_in,
                              void* d_out, int out_size, void* d_ws, size_t ws_size,
                              hipStream_t stream) {
    const int*   ids = (const int*)d_in[0];
    const float* emb = (const float*)d_in[1];
    float*       out = (float*)d_out;

    const int N = in_sizes[0] / LCODES;   // 65536 visits
    const int C = in_sizes[1] / DIM;      // 100000 codes

    // ws layout: [0..4KB) bmax[1024] | [4KB..4KB+4) qs | [8KB..) int8 table (C+1 rows)
    const size_t tab_off = 8192;
    const size_t need = tab_off + (size_t)(C + 1) * DIM;   // ~6.4 MB

    if (ws_size >= need) {
        unsigned*      bmax = (unsigned*)d_ws;
        float*         qsp  = (float*)((char*)d_ws + 4096);
        unsigned char* tab  = (unsigned char*)d_ws + tab_off;

        const long n4 = (long)C * DIM / 4;
        hipLaunchKernelGGL(amax_kernel, dim3(1024), dim3(256), 0, stream,
                           emb, bmax, n4);
        const int blocksA = (C + 31) / 32;
        hipLaunchKernelGGL(build_i8_kernel, dim3(blocksA), dim3(256), 0, stream,
                           emb, bmax, tab, qsp, C);
        // 4 visits per wave, 4 waves per block -> 16 visits per block
        const int blocksB = (N + 15) / 16;
        hipLaunchKernelGGL(visit_gather_i8q_kernel, dim3(blocksB), dim3(256), 0,
                           stream, ids, tab, qsp, out, N, C);
    } else {
        const int blocks = (N + 3) / 4;
        hipLaunchKernelGGL(visit_fp32_kernel, dim3(blocks), dim3(256), 0, stream,
                           ids, emb, out, N);
    }
}